// Round 5
// baseline (369.566 us; speedup 1.0000x reference)
//
#include <hip/hip_runtime.h>
#include <hip/hip_fp16.h>
#include <hip/hip_cooperative_groups.h>
#include <math.h>

namespace cg = cooperative_groups;

// LinearCaps2d, BATCH=256, N = B_TYPES*H*W = 2048, C=10, POSE=16, 3 routing iters.
// R17: fused cooperative kernel. R16 evidence: per-pass time invariant to grid
// decomposition at fixed totals (R12 68us @512blk == R16 65us @1024blk), all
// pipes <26% busy -> latency-bound on the 3x-repeated staging/barrier structure;
// plus ~45us of inter-kernel drain gaps (sum(kernels)=200 vs dur=247).
//   (1) ONE kernel, 256 blocks x 512 thr (1 block/CU, coop co-resident):
//       stage weight(16n)+poses(128b) to LDS ONCE (Ws 80K + xs 67K + tr 10K
//       = 157 KB of 160 KB/CU); 3 routing iters inside with grid.sync();
//   (2) zero block barriers inside a pass (LDS read-only after prologue);
//       passes 1-2 have NO staging at all;
//   (3) same verified math/layouts as R16: XOR-swizzled Ws, MFMA 16x16x16f16
//       votes, packed-f16 logits+softmax, wave-local transpose + full-line
//       atomic flush (128 adds/address, R12-verified contention);
//   (4) epilogue squash folded into the same kernel after the last sync.
// ws: s0,s1,s2 [40960] f32 (491 KB), same as R16.

typedef _Float16 f16;
typedef _Float16 f16x2 __attribute__((ext_vector_type(2)));
typedef _Float16 f16x4 __attribute__((ext_vector_type(4)));
typedef __fp16   h16x2 __attribute__((ext_vector_type(2)));
typedef float f32x4 __attribute__((ext_vector_type(4)));

__device__ __forceinline__ f16x2 pk(float a, float b) {
    h16x2 t = __builtin_amdgcn_cvt_pkrtz(a, b);
    return __builtin_bit_cast(f16x2, t);
}

#if __has_builtin(__builtin_amdgcn_fdot2)
__device__ __forceinline__ float FDOT2(f16x2 a, f16x2 b, float c) {
    return __builtin_amdgcn_fdot2(__builtin_bit_cast(h16x2, a),
                                  __builtin_bit_cast(h16x2, b), c, false);
}
#else
__device__ __forceinline__ float FDOT2(f16x2 a, f16x2 b, float c) {
    return c + (float)a[0] * (float)b[0] + (float)a[1] * (float)b[1];
}
#endif

// xs row stride (f16): 268 = 12 mod 64 -> dword stride 6 mod 32 -> 16 distinct
// banks across lo with only free 2-way aliasing (same scheme as verified XS_ROW=76).
constexpr int XS_ROW = 268;

__device__ __forceinline__ float xorsum4(float v) {
    v += __shfl_xor(v, 16, 64);
    v += __shfl_xor(v, 32, 64);
    return v;
}

// packed f16x2 cross-quad reduction: one shfl pair for two c's (verified R11)
__device__ __forceinline__ f16x2 xorsum4h(f16x2 v) {
    union { f16x2 h; int i; } u;
    union { int i; f16x2 h; } w;
    u.h = v; w.i = __shfl_xor(u.i, 16, 64); v = v + w.h;
    u.h = v; w.i = __shfl_xor(u.i, 32, 64); v = v + w.h;
    return v;
}

__device__ __forceinline__ f16x4 cvt4(float4 w) {
    f16x2 a = pk(w.x, w.y);
    f16x2 b = pk(w.z, w.w);
    f16x4 r; r[0] = a[0]; r[1] = a[1]; r[2] = b[0]; r[3] = b[1];
    return r;
}

// grid: 256 blocks = 128 n-groups (16 n) x 2 b-groups (128 b); 512 thr = 8 waves.
__global__ __launch_bounds__(512, 2)
void fused_k(const float* __restrict__ poses, const float* __restrict__ weight,
             const float* __restrict__ bias,
             float* __restrict__ s0, float* __restrict__ s1,
             float* __restrict__ s2, float* __restrict__ out)
{
    __shared__ f16   Ws[2560 * 16];      // 81920 B, XOR-swizzled columns, 16 n
    __shared__ f16   xs[128 * XS_ROW];   // 68608 B, 128 b x 16 n x 16 i
    __shared__ float tr[8 * 320];        // 10240 B, per-wave transpose scratch

    const int tid  = threadIdx.x;
    const int blk  = blockIdx.x;
    const int ngrp = blk >> 1;          // 128 n-groups (16 n each)
    const int b0   = (blk & 1) * 128;   // 2 b-groups
    const int wave = tid >> 6;
    const int lane = tid & 63;
    const int q    = lane >> 4;
    const int lo   = lane & 15;
    const int bg   = b0 + wave * 16;    // wave's global batch base

    // swizzle constants (lane-constant): physical col-quad = q ^ sigma(row),
    // sigma(row) = ((row>>1)^(row>>3))&3; row = (n*10+c)*16+lo so odd c flips ^2.
    const int sr  = ((lo >> 1) ^ (lo >> 3)) & 3;
    const int xqE = ((q ^ sr) & 3) * 4;          // even c
    const int xqO = ((q ^ sr ^ 2) & 3) * 4;      // odd c

    // ---- one-time staging: weight 16n slice (contiguous 160 KB) + poses slice
    {
        const float* wp = weight + (size_t)ngrp * 40960;
        const int wcol = (((tid & 3) ^ ((tid >> 3) ^ (tid >> 5))) & 3) * 4;
        float4 wreg[10];
        #pragma unroll
        for (int half = 0; half < 2; ++half) {
            #pragma unroll
            for (int k = 0; k < 10; ++k)
                wreg[k] = ((const float4*)wp)[tid + (half * 10 + k) * 512];
            #pragma unroll
            for (int k = 0; k < 10; ++k) {
                const int f = tid + (half * 10 + k) * 512;   // float4 idx in [0,10240)
                // row = f>>2 = (tid>>2)+128*(half*10+k): sigma bits k-invariant
                *(f16x4*)&Ws[(f >> 2) * 16 + wcol] = cvt4(wreg[k]);
            }
        }
        const int b_loc = tid >> 2, part = tid & 3;
        const float* xp = poses + (size_t)(b0 + b_loc) * 32768
                          + (size_t)ngrp * 256 + part * 64;
        float4 xreg[8];
        #pragma unroll
        for (int half = 0; half < 2; ++half) {
            #pragma unroll
            for (int j = 0; j < 8; ++j)
                xreg[j] = ((const float4*)xp)[half * 8 + j];
            #pragma unroll
            for (int j = 0; j < 8; ++j)
                *(f16x4*)&xs[b_loc * XS_ROW + part * 64 + (half * 8 + j) * 4]
                    = cvt4(xreg[j]);
        }
    }
    __syncthreads();

    cg::grid_group grid = cg::this_grid();

    #pragma unroll 1
    for (int pass = 0; pass < 3; ++pass) {
        float* dst = (pass == 0) ? s0 : (pass == 1) ? s1 : s2;
        const float fs = (pass == 0) ? 0.1f : 1.f;

        // ---- inline squash: vsp[c] = v[b=bg+lo][c][o=q*4..q*4+3], packed f16
        f16x2 vsp[10][2];
        if (pass >= 1) {
            const int rowb = (bg + lo) * 10;
            #pragma unroll
            for (int c = 0; c < 10; ++c) {
                float4 bb = *(const float4*)(bias + c * 16 + q * 4);
                const size_t off = (size_t)(rowb + c) * 16 + q * 4;
                float4 sa = *(const float4*)(s0 + off);
                float t0 = sa.x + bb.x, t1 = sa.y + bb.y;
                float t2 = sa.z + bb.z, t3 = sa.w + bb.w;
                float n2 = xorsum4(t0*t0 + t1*t1 + t2*t2 + t3*t3);
                float sc = n2 / (1.f + n2) * rsqrtf(n2 + 1e-8f);
                float v0 = sc*t0, v1 = sc*t1, v2 = sc*t2, v3 = sc*t3;
                if (pass == 2) {
                    float4 ua = *(const float4*)(s1 + off);
                    float u0 = ua.x + bb.x, u1 = ua.y + bb.y;
                    float u2 = ua.z + bb.z, u3 = ua.w + bb.w;
                    float m2 = xorsum4(u0*u0 + u1*u1 + u2*u2 + u3*u3);
                    float sc2 = m2 / (1.f + m2) * rsqrtf(m2 + 1e-8f);
                    v0 += sc2*u0; v1 += sc2*u1; v2 += sc2*u2; v3 += sc2*u3;
                }
                vsp[c][0] = pk(v0, v1);
                vsp[c][1] = pk(v2, v3);
            }
        }

        f32x4 acc[10];
        #pragma unroll
        for (int c = 0; c < 10; ++c) acc[c] = (f32x4){0.f, 0.f, 0.f, 0.f};

        #pragma unroll 2
        for (int n = 0; n < 16; ++n) {
            // votes^T fragments V[c][r] = votes[b=bg+lo][c][o=q*4+r] (R7 layout),
            // packed to f16 immediately to keep register pressure low.
            f16x4 bx = *(const f16x4*)&xs[(wave * 16 + lo) * XS_ROW + n * 16 + q * 4];
            f16x2 Vh[10][2];
            #pragma unroll
            for (int c = 0; c < 10; ++c) {
                f16x4 aw = *(const f16x4*)&Ws[((n * 10 + c) * 16 + lo) * 16
                                              + ((c & 1) ? xqO : xqE)];
                f32x4 V = __builtin_amdgcn_mfma_f32_16x16x16f16(
                    aw, bx, (f32x4){0.f, 0.f, 0.f, 0.f}, 0, 0, 0);
                Vh[c][0] = pk(V[0], V[1]);
                Vh[c][1] = pk(V[2], V[3]);
            }

            float cfv[10];
            #pragma unroll
            for (int c = 0; c < 10; ++c) cfv[c] = 1.f;
            if (pass >= 1) {
                // logits: fdot2 on packed votes vs vsp; packed cross-quad reduce
                float lg[10];
                #pragma unroll
                for (int cp = 0; cp < 5; ++cp) {
                    const int c0 = cp * 2, c1 = cp * 2 + 1;
                    float p0 = FDOT2(Vh[c0][0], vsp[c0][0], 0.f);
                    p0 = FDOT2(Vh[c0][1], vsp[c0][1], p0);
                    float p1 = FDOT2(Vh[c1][0], vsp[c1][0], 0.f);
                    p1 = FDOT2(Vh[c1][1], vsp[c1][1], p1);
                    f16x2 pr = xorsum4h(pk(p0, p1));
                    lg[c0] = (float)pr[0];
                    lg[c1] = (float)pr[1];
                }
                float m = lg[0];
                #pragma unroll
                for (int c = 1; c < 10; ++c) m = fmaxf(m, lg[c]);
                float sum = 0.f;
                #pragma unroll
                for (int c = 0; c < 10; ++c) { lg[c] = __expf(lg[c] - m); sum += lg[c]; }
                const float inv = 1.f / sum;
                #pragma unroll
                for (int c = 0; c < 10; ++c) cfv[c] = lg[c] * inv;
            }

            // s-accumulate straight from packed votes
            #pragma unroll
            for (int c = 0; c < 10; ++c) {
                acc[c][0] = fmaf(cfv[c], (float)Vh[c][0][0], acc[c][0]);
                acc[c][1] = fmaf(cfv[c], (float)Vh[c][0][1], acc[c][1]);
                acc[c][2] = fmaf(cfv[c], (float)Vh[c][1][0], acc[c][2]);
                acc[c][3] = fmaf(cfv[c], (float)Vh[c][1][1], acc[c][3]);
            }
        }

        // ---- wave-local LDS transpose (b<->o) + full-line atomic flush.
        // tr is a dedicated per-wave buffer: wave-synchronous in-order DS ops,
        // no barrier needed (same idiom as verified R7-R16).
        float* trw = tr + wave * 320;    // 320 floats/wave, stride-20 rows
        #pragma unroll
        for (int c = 0; c < 10; ++c) {
            *(float4*)&trw[lo * 20 + q * 4] =
                (float4){acc[c][0], acc[c][1], acc[c][2], acc[c][3]};
            float r0 = trw[(q * 4 + 0) * 20 + lo];
            float r1 = trw[(q * 4 + 1) * 20 + lo];
            float r2 = trw[(q * 4 + 2) * 20 + lo];
            float r3 = trw[(q * 4 + 3) * 20 + lo];
            float* sp = dst + ((size_t)(bg + q * 4) * 10 + c) * 16 + lo;
            unsafeAtomicAdd(sp + 0 * 160, fs * r0);
            unsafeAtomicAdd(sp + 1 * 160, fs * r1);
            unsafeAtomicAdd(sp + 2 * 160, fs * r2);
            unsafeAtomicAdd(sp + 3 * 160, fs * r3);
        }

        __threadfence();
        grid.sync();
    }

    // ---- epilogue squash: 2560 rows, one (b,c) per thread (verified R3/R7).
    const int t = blk * 512 + tid;
    if (t < 2560) {
        const int c = t % 10;
        const float* sp = s2 + (size_t)t * 16;
        const float* bp = bias + c * 16;
        float sv[16];
        float n2 = 0.f;
        #pragma unroll
        for (int o = 0; o < 16; ++o) { float v = sp[o] + bp[o]; sv[o] = v; n2 += v * v; }
        const float scale = n2 / (1.f + n2) * rsqrtf(n2 + 1e-8f);
        float a2 = 0.f;
        #pragma unroll
        for (int o = 0; o < 16; ++o) {
            float v = scale * sv[o];
            out[(size_t)t * 16 + o] = v;
            a2 += v * v;
        }
        out[40960 + t] = sqrtf(a2 + 1e-8f);
    }
}

extern "C" void kernel_launch(void* const* d_in, const int* in_sizes, int n_in,
                              void* d_out, int out_size, void* d_ws, size_t ws_size,
                              hipStream_t stream)
{
    const float* poses  = (const float*)d_in[0];
    // d_in[1] (input_caps_activations) unused by the reference.
    const float* weight = (const float*)d_in[2];
    const float* bias   = (const float*)d_in[3];
    float* out = (float*)d_out;
    float* s0 = (float*)d_ws;
    float* s1 = s0 + 40960;
    float* s2 = s1 + 40960;

    (void)hipMemsetAsync(d_ws, 0, 3 * 40960 * sizeof(float), stream);

    void* args[] = {(void*)&poses, (void*)&weight, (void*)&bias,
                    (void*)&s0, (void*)&s1, (void*)&s2, (void*)&out};
    hipError_t err = hipLaunchCooperativeKernel((const void*)fused_k,
                                                dim3(256), dim3(512),
                                                args, 0, stream);
    if (err != hipSuccess) {
        // fallback: grid == CU count with 1 block/CU-sized LDS -> de-facto
        // co-resident; grid.sync still safe in practice.
        fused_k<<<256, 512, 0, stream>>>(poses, weight, bias, s0, s1, s2, out);
    }
}

// Round 6
// 263.169 us; speedup vs baseline: 1.4043x; 1.4043x over previous
//
#include <hip/hip_runtime.h>
#include <hip/hip_fp16.h>
#include <math.h>

// LinearCaps2d, BATCH=256, N = B_TYPES*H*W = 2048, C=10, POSE=16, 3 routing iters.
// R18: revert R17's fused coop kernel (grid.sync pathology: 41ms outlier, 1 blk/CU,
// 298us steady). Back to R16 skeleton (proven 65us/pass, clean traffic) and attack
// the measured binder: staging serialization (pass0==pass2 at 65us, all pipes <26%).
//   (1) weights staged via __builtin_amdgcn_global_load_lds width=16 into f32 LDS
//       (no VGPR round trip, no cvt chain); 2-n tiles, DOUBLE-buffered, one barrier
//       per tile -> tile t+2's loads are in flight across a full compute phase;
//   (2) swizzle moved to the GLOBAL source address (linear LDS dest, rule 21);
//       read side uses the same involution; f32->f16 cvt at read (2 pk per frag);
//   (3) poses: no LDS at all -- each lane loads its own 8 B-fragments
//       (float4->cvt4, 16 VGPR), the exact values R16's xs path produced;
//   (4) LDS 40960 B -> 3 blocks/CU; tr-scratch reuses buf0 after last barrier;
//   (5) keep (256,2) (proven 128-reg no-spill), grid 1024, atomic flush, epi_k.
// ws: s0,s1,s2 [40960] f32 (491 KB).

typedef _Float16 f16;
typedef _Float16 f16x2 __attribute__((ext_vector_type(2)));
typedef _Float16 f16x4 __attribute__((ext_vector_type(4)));
typedef __fp16   h16x2 __attribute__((ext_vector_type(2)));
typedef float f32x4 __attribute__((ext_vector_type(4)));

__device__ __forceinline__ f16x2 pk(float a, float b) {
    h16x2 t = __builtin_amdgcn_cvt_pkrtz(a, b);
    return __builtin_bit_cast(f16x2, t);
}

#if __has_builtin(__builtin_amdgcn_fdot2)
__device__ __forceinline__ float FDOT2(f16x2 a, f16x2 b, float c) {
    return __builtin_amdgcn_fdot2(__builtin_bit_cast(h16x2, a),
                                  __builtin_bit_cast(h16x2, b), c, false);
}
#else
__device__ __forceinline__ float FDOT2(f16x2 a, f16x2 b, float c) {
    return c + (float)a[0] * (float)b[0] + (float)a[1] * (float)b[1];
}
#endif

__device__ __forceinline__ float xorsum4(float v) {
    v += __shfl_xor(v, 16, 64);
    v += __shfl_xor(v, 32, 64);
    return v;
}

// packed f16x2 cross-quad reduction: one shfl pair for two c's (verified R11)
__device__ __forceinline__ f16x2 xorsum4h(f16x2 v) {
    union { f16x2 h; int i; } u;
    union { int i; f16x2 h; } w;
    u.h = v; w.i = __shfl_xor(u.i, 16, 64); v = v + w.h;
    u.h = v; w.i = __shfl_xor(u.i, 32, 64); v = v + w.h;
    return v;
}

__device__ __forceinline__ f16x4 cvt4(float4 w) {
    f16x2 a = pk(w.x, w.y);
    f16x2 b = pk(w.z, w.w);
    f16x4 r; r[0] = a[0]; r[1] = a[1]; r[2] = b[0]; r[3] = b[1];
    return r;
}

#if __has_builtin(__builtin_amdgcn_global_load_lds)
#define HAS_GLL 1
__device__ __forceinline__ void gll16(const float* g, float* l) {
    __builtin_amdgcn_global_load_lds(
        (const __attribute__((address_space(1))) void*)g,
        (__attribute__((address_space(3))) void*)l, 16, 0, 0);
}
#else
#define HAS_GLL 0
#endif

// sigma(row) for the quad swizzle: bit-disjoint adds proven -> sigma = sr ^ 2*(c&1)
__device__ __forceinline__ int sigma_row(int row) {
    return ((row >> 1) ^ (row >> 3)) & 3;
}

// grid: 1024 blocks = 256 n-groups (8 n) x 4 b-groups (64 b); 256 thr = 4 waves.
// Consecutive partners share a weight slice; L3 absorbs the 4-way re-fetch (R12/R16).
template<int PASS>
__global__ __launch_bounds__(256, 2)
void pass_k(const float* __restrict__ poses, const float* __restrict__ weight,
            const float* __restrict__ bias,
            const float* __restrict__ sp0, const float* __restrict__ sp1,
            float* __restrict__ s_dst)
{
    // two 2-n weight tiles in f32: [320 rows][16 f32] each, quad-swizzled via source
    __shared__ float Ws32[2 * 5120];   // 40960 B total

    const int tid  = threadIdx.x;
    const int blk  = blockIdx.x;
    const int ngrp = blk >> 2;          // 256 n-groups (8 n each)
    const int b0   = (blk & 3) * 64;    // 4 b-groups
    const int wave = tid >> 6;
    const int lane = tid & 63;
    const int q    = lane >> 4;
    const int lo   = lane & 15;
    const int bg   = b0 + wave * 16;    // wave's global batch base

    // read-side swizzle (lane-constant): physical quad = q ^ sigma(row),
    // sigma(row)&3 = sr ^ 2*(c&1) for row=(n*10+c)*16+lo (bit-disjoint adds).
    const int sr  = ((lo >> 1) ^ (lo >> 3)) & 3;
    const int qE  = (q ^ sr) & 3;        // even c quad
    const int qO  = qE ^ 2;              // odd c quad

    // ---- weight staging: 2-n tile = 1280 float4; 5 per thread (f = tid + k*256).
    const float* wbase = weight + (size_t)ngrp * 8 * 2560;   // 8 n x 160 x 16 f32
    auto issue_tile = [&](int t, int buf) {
        const float* wt = wbase + (size_t)t * 5120;          // 2 n
        float* db = &Ws32[buf * 5120 + (tid & 192) * 4];     // wave-uniform comp below
        #pragma unroll
        for (int k = 0; k < 5; ++k) {
            const int f   = tid + k * 256;
            const int row = f >> 2;
            const int sq  = (tid & 3) ^ sigma_row(row);      // source quad (involution)
            const float* src = wt + (size_t)row * 16 + sq * 4;
#if HAS_GLL
            // LDS dest: wave-uniform base + lane*16B == &Ws32[buf*5120 + f*4]
            float* dst = &Ws32[buf * 5120 + (k * 256 + wave * 64) * 4];
            gll16(src, dst);
#else
            float4 v = *(const float4*)src;
            *(float4*)&Ws32[buf * 5120 + f * 4] = v;
#endif
        }
        (void)db;
    };

    // ---- issue first two tiles immediately (critical path), then overlap the rest
    issue_tile(0, 0);
    issue_tile(1, 1);

    // ---- poses: each lane loads exactly its own 8 MFMA B-fragments (no LDS).
    // bxh[n] = f16(poses[b=bg+lo][n_global=ngrp*8+n][i=q*4..q*4+3])  (==R16 xs values)
    f16x4 bxh[8];
    {
        const float4* pp = (const float4*)poses;
        const size_t rowb = (size_t)(bg + lo) * 8192 + q;    // float4 units
        #pragma unroll
        for (int n = 0; n < 8; ++n)
            bxh[n] = cvt4(pp[rowb + (size_t)(ngrp * 8 + n) * 4]);
    }

    // ---- inline squash: vsp[c] = v[b=bg+lo][c][o=q*4..q*4+3], packed f16
    f16x2 vsp[10][2];
    if (PASS >= 1) {
        const int rowb = (bg + lo) * 10;
        #pragma unroll
        for (int c = 0; c < 10; ++c) {
            float4 bb = *(const float4*)(bias + c * 16 + q * 4);
            const size_t off = (size_t)(rowb + c) * 16 + q * 4;
            float4 sa = *(const float4*)(sp0 + off);
            float t0 = sa.x + bb.x, t1 = sa.y + bb.y;
            float t2 = sa.z + bb.z, t3 = sa.w + bb.w;
            float n2 = xorsum4(t0*t0 + t1*t1 + t2*t2 + t3*t3);
            float sc = n2 / (1.f + n2) * rsqrtf(n2 + 1e-8f);
            float v0 = sc*t0, v1 = sc*t1, v2 = sc*t2, v3 = sc*t3;
            if (PASS == 2) {
                float4 ua = *(const float4*)(sp1 + off);
                float u0 = ua.x + bb.x, u1 = ua.y + bb.y;
                float u2 = ua.z + bb.z, u3 = ua.w + bb.w;
                float m2 = xorsum4(u0*u0 + u1*u1 + u2*u2 + u3*u3);
                float sc2 = m2 / (1.f + m2) * rsqrtf(m2 + 1e-8f);
                v0 += sc2*u0; v1 += sc2*u1; v2 += sc2*u2; v3 += sc2*u3;
            }
            vsp[c][0] = pk(v0, v1);
            vsp[c][1] = pk(v2, v3);
        }
    }

    f32x4 acc[10];
    #pragma unroll
    for (int c = 0; c < 10; ++c) acc[c] = (f32x4){0.f, 0.f, 0.f, 0.f};

    __syncthreads();   // drains tile0+tile1 loads

    // ---- 4 tiles x 2 n each; one barrier per tile; t+2 loads fly over compute(t+1)
    #pragma unroll 1
    for (int t = 0; t < 4; ++t) {
        const float4* wsf = (const float4*)&Ws32[(t & 1) * 5120];

        #pragma unroll
        for (int nl = 0; nl < 2; ++nl) {
            const int n = t * 2 + nl;
            f16x4 bx = bxh[n];
            f16x2 Vh[10][2];
            #pragma unroll
            for (int c = 0; c < 10; ++c) {
                const int row = (nl * 10 + c) * 16 + lo;
                float4 aw4 = wsf[row * 4 + ((c & 1) ? qO : qE)];
                f16x4 aw = cvt4(aw4);
                f32x4 V = __builtin_amdgcn_mfma_f32_16x16x16f16(
                    aw, bx, (f32x4){0.f, 0.f, 0.f, 0.f}, 0, 0, 0);
                Vh[c][0] = pk(V[0], V[1]);
                Vh[c][1] = pk(V[2], V[3]);
            }

            float cfv[10];
            if (PASS >= 1) {
                float lg[10];
                #pragma unroll
                for (int cp = 0; cp < 5; ++cp) {
                    const int c0 = cp * 2, c1 = cp * 2 + 1;
                    float p0 = FDOT2(Vh[c0][0], vsp[c0][0], 0.f);
                    p0 = FDOT2(Vh[c0][1], vsp[c0][1], p0);
                    float p1 = FDOT2(Vh[c1][0], vsp[c1][0], 0.f);
                    p1 = FDOT2(Vh[c1][1], vsp[c1][1], p1);
                    f16x2 pr = xorsum4h(pk(p0, p1));
                    lg[c0] = (float)pr[0];
                    lg[c1] = (float)pr[1];
                }
                float m = lg[0];
                #pragma unroll
                for (int c = 1; c < 10; ++c) m = fmaxf(m, lg[c]);
                float sum = 0.f;
                #pragma unroll
                for (int c = 0; c < 10; ++c) { lg[c] = __expf(lg[c] - m); sum += lg[c]; }
                const float inv = 1.f / sum;
                #pragma unroll
                for (int c = 0; c < 10; ++c) cfv[c] = lg[c] * inv;
            }

            #pragma unroll
            for (int c = 0; c < 10; ++c) {
                const float w = (PASS == 0) ? 1.f : cfv[c];
                acc[c][0] = fmaf(w, (float)Vh[c][0][0], acc[c][0]);
                acc[c][1] = fmaf(w, (float)Vh[c][0][1], acc[c][1]);
                acc[c][2] = fmaf(w, (float)Vh[c][1][0], acc[c][2]);
                acc[c][3] = fmaf(w, (float)Vh[c][1][1], acc[c][3]);
            }
        }

        __syncthreads();                     // all waves done with buf[t&1]
        if (t + 2 < 4) issue_tile(t + 2, t & 1);   // refill; drains at NEXT barrier
    }

    // ---- wave-local LDS transpose (b<->o) + full-line atomic flush.
    // Reuse buf0 (last barrier above guarantees all reads done).
    float* tr = (float*)Ws32 + wave * 320;   // 320 floats/wave, stride-20 rows
    const float fs = (PASS == 0) ? 0.1f : 1.f;
    #pragma unroll
    for (int c = 0; c < 10; ++c) {
        *(float4*)&tr[lo * 20 + q * 4] =
            (float4){acc[c][0], acc[c][1], acc[c][2], acc[c][3]};
        float r0 = tr[(q * 4 + 0) * 20 + lo];
        float r1 = tr[(q * 4 + 1) * 20 + lo];
        float r2 = tr[(q * 4 + 2) * 20 + lo];
        float r3 = tr[(q * 4 + 3) * 20 + lo];
        float* sp = s_dst + ((size_t)(bg + q * 4) * 10 + c) * 16 + lo;
        unsafeAtomicAdd(sp + 0 * 160, fs * r0);
        unsafeAtomicAdd(sp + 1 * 160, fs * r1);
        unsafeAtomicAdd(sp + 2 * 160, fs * r2);
        unsafeAtomicAdd(sp + 3 * 160, fs * r3);
    }
}

// final squash: 2560 rows, one (b,c) per thread (verified R3/R7).
__global__ __launch_bounds__(256)
void epi_k(const float* __restrict__ s2, const float* __restrict__ bias,
           float* __restrict__ out)
{
    const int t = blockIdx.x * 256 + threadIdx.x;
    if (t >= 2560) return;
    const int c = t % 10;
    const float* sp = s2 + (size_t)t * 16;
    const float* bp = bias + c * 16;
    float sv[16];
    float n2 = 0.f;
    #pragma unroll
    for (int o = 0; o < 16; ++o) { float v = sp[o] + bp[o]; sv[o] = v; n2 += v * v; }
    const float scale = n2 / (1.f + n2) * rsqrtf(n2 + 1e-8f);
    float a2 = 0.f;
    #pragma unroll
    for (int o = 0; o < 16; ++o) {
        float v = scale * sv[o];
        out[(size_t)t * 16 + o] = v;
        a2 += v * v;
    }
    out[40960 + t] = sqrtf(a2 + 1e-8f);
}

extern "C" void kernel_launch(void* const* d_in, const int* in_sizes, int n_in,
                              void* d_out, int out_size, void* d_ws, size_t ws_size,
                              hipStream_t stream)
{
    const float* poses  = (const float*)d_in[0];
    // d_in[1] (input_caps_activations) unused by the reference.
    const float* weight = (const float*)d_in[2];
    const float* bias   = (const float*)d_in[3];
    float* out = (float*)d_out;
    float* s0 = (float*)d_ws;
    float* s1 = s0 + 40960;
    float* s2 = s1 + 40960;

    (void)hipMemsetAsync(d_ws, 0, 3 * 40960 * sizeof(float), stream);

    pass_k<0><<<1024, 256, 0, stream>>>(poses, weight, bias, nullptr, nullptr, s0);
    pass_k<1><<<1024, 256, 0, stream>>>(poses, weight, bias, s0, nullptr, s1);
    pass_k<2><<<1024, 256, 0, stream>>>(poses, weight, bias, s0, s1, s2);
    epi_k<<<10, 256, 0, stream>>>(s2, bias, out);
}